// Round 13
// baseline (104.579 us; speedup 1.0000x reference)
//
#include <hip/hip_runtime.h>
#include <stdint.h>

#define C_IN 256
#define HW   56
#define HW2  3136          // 56*56
#define SPAN 2304          // 9*256
#define TS   16
#define BKT  32

typedef __attribute__((ext_vector_type(8)))  short short8;
typedef __attribute__((ext_vector_type(4)))  float f32x4;
typedef __attribute__((ext_vector_type(16))) float f32x16;
typedef float f32x4u __attribute__((ext_vector_type(4), aligned(4)));   // 4B-aligned vector load

// d_ws layout: [0..127]: rows (32 x int32). [512 ...]: Wpack ushort[73728]

// ---------------------------------------------------------------------------
// Kernel 1: hash -> 32 gathered row ids (byte-identical to all PASS rounds).
// ---------------------------------------------------------------------------
__global__ void hash_rows_kernel(const float* __restrict__ x,
                                 const float* __restrict__ a,
                                 const int*   __restrict__ table,
                                 int*         __restrict__ rows_out) {
    __shared__ float rd[256];
    __shared__ float rn[256];
    const int t = threadIdx.x;
    float dv = 0.f, nq = 0.f;
    for (int k = t; k < SPAN; k += 256) {
        const int p = k >> 8;
        const int c = k & 255;
        const int i = p / 3, j = p % 3;
        float v = 0.f;
        if (i >= 1 && j >= 1) v = x[c * HW2 + (i - 1) * HW + (j - 1)];
        dv += a[k] * v;
        nq += v * v;
    }
    rd[t] = dv; rn[t] = nq;
    __syncthreads();
    for (int s = 128; s > 0; s >>= 1) {
        if (t < s) { rd[t] += rd[t + s]; rn[t] += rn[t + s]; }
        __syncthreads();
    }
    if (t == 0) {
        const float nrm = sqrtf(rn[0]);
        const float sv  = rd[0] / nrm
                        + 0.5f * (a[SPAN] + a[SPAN+1] + a[SPAN+2] + a[SPAN+3] + a[SPAN+4]);
        const int idx = ((int)fabsf(floorf(sv))) % TS;
        #pragma unroll
        for (int b = 0; b < BKT; ++b) rows_out[b] = table[idx * BKT + b];
    }
}

// ---------------------------------------------------------------------------
// Kernel 2: build Wpack for 32x32x16 A-fragments (byte-identical to round-12
// PASS). Chunk Q = ccb*18 + p*2 + ch16 (144 chunks of K=16).
// Lane l elem j: A[brow = l&31][k = p*256 + ccb*32 + ch16*16 + (l>>5)*8 + j].
// ---------------------------------------------------------------------------
__global__ void build_wpack_kernel(const float* __restrict__ kernels,
                                   const int*   __restrict__ rows,
                                   unsigned short* __restrict__ wp) {
    const int idx   = blockIdx.x * 256 + threadIdx.x;   // 0..73727
    const int j     = idx & 7;
    const int l     = (idx >> 3) & 63;
    const int Q     = idx >> 9;          // 0..143
    const int ccb   = Q / 18;
    const int rem   = Q % 18;
    const int p     = rem >> 1;
    const int ch16  = rem & 1;
    const int brow  = l & 31;
    const int khalf = l >> 5;
    const int k     = p * 256 + ccb * 32 + ch16 * 16 + khalf * 8 + j;
    const int row   = rows[brow];
    const float v = kernels[(size_t)row * SPAN + k] * 16.0f;
    unsigned u = __builtin_bit_cast(unsigned, v);
    u = (u + 0x7fffu + ((u >> 16) & 1u)) >> 16;       // RNE fp32->bf16
    wp[idx] = (unsigned short)u;
}

// ---------------------------------------------------------------------------
// Kernel 3: implicit-GEMM via mfma_f32_32x32x16_bf16 — round-12 PASS body,
// with (a) block's A-slice staged once in LDS (round-2-proven typed short8
// vector-write/vector-read idiom; ccb is block-uniform so all 4 waves share
// the same 18 chunks = 1152 short8 = 18KB; single barrier at kernel start),
// (b) __launch_bounds__(256,8) to force regs <= 64 (the m69 occupancy cliff:
// round-12's 68 regs capped us at 4 waves/SIMD).
// ---------------------------------------------------------------------------
__global__ __launch_bounds__(256, 8)
void alsh_mfma_kernel(const float* __restrict__ x,
                      const unsigned short* __restrict__ wp,
                      float* __restrict__ out) {
    __shared__ short8 As[1152];                 // 18 chunks x 64 lanes, 18432 B

    const int b   = blockIdx.x;                 // 0..3135
    const int r   = b & 7;                      // XCD under round-robin heuristic
    const int i   = b >> 3;                     // 0..391
    const int ct  = r * 49 + (i >> 3);          // column-tile 0..391 (bijective)
    const int ccb = i & 7;                      // K-slice = one 32-ch block

    const int t = threadIdx.x;
    // ---- stage A-slice: units [ccb*1152, ccb*1152+1152) of wp ----
    {
        const short8* src = (const short8*)wp + ccb * 1152;
        #pragma unroll
        for (int it = 0; it < 5; ++it) {
            const int u = it * 256 + t;
            if (u < 1152) As[u] = src[u];
        }
    }
    __syncthreads();

    const int lane  = t & 63;
    const int wid   = t >> 6;                   // 0..3
    const int col   = lane & 31;                // B-col / D-col
    const int khalf = lane >> 5;                // k-half 0..1
    const int s0    = ct * 128 + wid * 32;      // wave's base column
    const int n     = s0 / HW2;                 // wave-uniform (3136 = 98*32)
    const int s0img = s0 - n * HW2;
    const int sl    = s0img + col;              // lane's spatial idx in image
    const int h     = sl / HW;
    const int w     = sl - h * HW;
    const float* xn = x + (size_t)n * (C_IN * HW2);

    f32x16 acc = {0.f,0.f,0.f,0.f, 0.f,0.f,0.f,0.f, 0.f,0.f,0.f,0.f, 0.f,0.f,0.f,0.f};

    const int cc = ccb * 32;
    #pragma unroll
    for (int dd = 0; dd < 3; ++dd) {            // di = dd-1
        const int di     = dd - 1;
        const int rowpos = sl + di * HW;        // pos at dj=0
        const int posm   = rowpos - 1;          // window base (dj=-1)
        const int pc     = posm < 0 ? 0 : (posm > HW2 - 4 ? HW2 - 4 : posm);
        const bool shifted = (pc != posm);      // edge lanes only
        const int ih = h + di;

        #pragma unroll
        for (int ch16 = 0; ch16 < 2; ++ch16) {
            f32x4 V[8];
            #pragma unroll
            for (int j = 0; j < 8; ++j) {
                const int ch = cc + ch16 * 16 + khalf * 8 + j;
                V[j] = *(const f32x4u*)(xn + (size_t)ch * HW2 + pc);
            }

            #pragma unroll
            for (int dd2 = 0; dd2 < 3; ++dd2) { // dj = dd2-1
                const int dj = dd2 - 1;
                const int iw = w + dj;
                const bool ok = ((unsigned)ih < (unsigned)HW) & ((unsigned)iw < (unsigned)HW);
                const int voff = rowpos + dj;

                short8 bf;
                #pragma unroll
                for (int j = 0; j < 8; ++j) {
                    float v = V[j][dd2];        // = x[ch][voff] when !shifted
                    if (shifted) {              // exec-masked scalar fallback
                        const int vc = voff < 0 ? 0 : (voff > HW2 - 1 ? HW2 - 1 : voff);
                        v = xn[(size_t)(cc + ch16 * 16 + khalf * 8 + j) * HW2 + vc];
                    }
                    v = ok ? v : 0.f;
                    const unsigned u = __builtin_bit_cast(unsigned, v);
                    bf[j] = (short)((u + 0x8000u) >> 16);   // fp32->bf16 round
                }

                const int Ql = (dd * 3 + dd2) * 2 + ch16;   // local chunk 0..17
                const short8 a = As[Ql * 64 + lane];
                acc = __builtin_amdgcn_mfma_f32_32x32x16_bf16(a, bf, acc, 0, 0, 0);
            }
        }
    }

    // C/D: col = lane&31 (in sl), row = (reg&3) + 8*(reg>>2) + 4*khalf
    float* ob = out + (size_t)n * (BKT * HW2) + sl;
    #pragma unroll
    for (int i2 = 0; i2 < 16; ++i2) {
        const int b0 = (i2 & 3) + 8 * (i2 >> 2) + 4 * khalf;
        atomicAdd(&ob[(size_t)b0 * HW2], acc[i2]);
    }
}

// ---------------------------------------------------------------------------
extern "C" void kernel_launch(void* const* d_in, const int* in_sizes, int n_in,
                              void* d_out, int out_size, void* d_ws, size_t ws_size,
                              hipStream_t stream) {
    const float* x       = (const float*)d_in[0];
    const float* kernels = (const float*)d_in[1];
    const float* a       = (const float*)d_in[2];
    const int*   table   = (const int*)d_in[3];
    float* out = (float*)d_out;
    int*   rows = (int*)d_ws;
    unsigned short* wpack = (unsigned short*)((char*)d_ws + 512);

    hipMemsetAsync(d_out, 0, (size_t)out_size * sizeof(float), stream);
    hipLaunchKernelGGL(hash_rows_kernel, dim3(1), dim3(256), 0, stream,
                       x, a, table, rows);
    hipLaunchKernelGGL(build_wpack_kernel, dim3(288), dim3(256), 0, stream,
                       kernels, rows, wpack);
    hipLaunchKernelGGL(alsh_mfma_kernel, dim3(3136), dim3(256), 0, stream,
                       x, wpack, out);
}

// Round 14
// 49.211 us; speedup vs baseline: 2.1251x; 2.1251x over previous
//
#include <hip/hip_runtime.h>
#include <stdint.h>

#define C_IN 256
#define HW   56
#define HW2  3136          // 56*56
#define SPAN 2304          // 9*256
#define TS   16
#define BKT  32

typedef __attribute__((ext_vector_type(8)))  short short8;
typedef __attribute__((ext_vector_type(4)))  float f32x4;
typedef __attribute__((ext_vector_type(16))) float f32x16;
typedef float f32x4u __attribute__((ext_vector_type(4), aligned(4)));   // 4B-aligned vector load

// d_ws layout: [0..127]: rows (32 x int32). [512 ...]: Wpack ushort[73728]

// ---------------------------------------------------------------------------
// Kernel 1: hash -> 32 gathered row ids (byte-identical to all PASS rounds).
// ---------------------------------------------------------------------------
__global__ void hash_rows_kernel(const float* __restrict__ x,
                                 const float* __restrict__ a,
                                 const int*   __restrict__ table,
                                 int*         __restrict__ rows_out) {
    __shared__ float rd[256];
    __shared__ float rn[256];
    const int t = threadIdx.x;
    float dv = 0.f, nq = 0.f;
    for (int k = t; k < SPAN; k += 256) {
        const int p = k >> 8;
        const int c = k & 255;
        const int i = p / 3, j = p % 3;
        float v = 0.f;
        if (i >= 1 && j >= 1) v = x[c * HW2 + (i - 1) * HW + (j - 1)];
        dv += a[k] * v;
        nq += v * v;
    }
    rd[t] = dv; rn[t] = nq;
    __syncthreads();
    for (int s = 128; s > 0; s >>= 1) {
        if (t < s) { rd[t] += rd[t + s]; rn[t] += rn[t + s]; }
        __syncthreads();
    }
    if (t == 0) {
        const float nrm = sqrtf(rn[0]);
        const float sv  = rd[0] / nrm
                        + 0.5f * (a[SPAN] + a[SPAN+1] + a[SPAN+2] + a[SPAN+3] + a[SPAN+4]);
        const int idx = ((int)fabsf(floorf(sv))) % TS;
        #pragma unroll
        for (int b = 0; b < BKT; ++b) rows_out[b] = table[idx * BKT + b];
    }
}

// ---------------------------------------------------------------------------
// Kernel 2: build Wpack for 32x32x16 A-fragments (byte-identical to round-12
// PASS). Chunk Q = ccb*18 + p*2 + ch16 (144 chunks of K=16).
// Lane l elem j: A[brow = l&31][k = p*256 + ccb*32 + ch16*16 + (l>>5)*8 + j].
// ---------------------------------------------------------------------------
__global__ void build_wpack_kernel(const float* __restrict__ kernels,
                                   const int*   __restrict__ rows,
                                   unsigned short* __restrict__ wp) {
    const int idx   = blockIdx.x * 256 + threadIdx.x;   // 0..73727
    const int j     = idx & 7;
    const int l     = (idx >> 3) & 63;
    const int Q     = idx >> 9;          // 0..143
    const int ccb   = Q / 18;
    const int rem   = Q % 18;
    const int p     = rem >> 1;
    const int ch16  = rem & 1;
    const int brow  = l & 31;
    const int khalf = l >> 5;
    const int k     = p * 256 + ccb * 32 + ch16 * 16 + khalf * 8 + j;
    const int row   = rows[brow];
    const float v = kernels[(size_t)row * SPAN + k] * 16.0f;
    unsigned u = __builtin_bit_cast(unsigned, v);
    u = (u + 0x7fffu + ((u >> 16) & 1u)) >> 16;       // RNE fp32->bf16
    wp[idx] = (unsigned short)u;
}

// ---------------------------------------------------------------------------
// Kernel 3: implicit-GEMM via mfma_f32_32x32x16_bf16 — round-12 PASS inner
// body, with IN-BLOCK K-REDUCE instead of split-K atomics:
//   block = 512 threads = 8 waves, ONE 32-column tile; wave wid computes
//   k-slice ccb = wid (18 MFMA, r12-identical B/A paths).
//   Epilogue: wave -> private 4KB LDS region (typed float scalar writes,
//   hash-kernel-proven idiom; 2 lanes/bank = free), one barrier, then the
//   512 threads sum 8 partials per output and store non-atomically.
//   Kills: atomic RMW write amplification (r13: 160MB), the memset dispatch,
//   and the 2x write floor of split-K (r12: 50MB -> 25MB).
//   Grid 1568 = 8*196, XCD-chunked. __launch_bounds__(512,4): <=128 VGPR,
//   2 blocks/CU, 32KB LDS/block.
// ---------------------------------------------------------------------------
__global__ __launch_bounds__(512, 4)
void alsh_mfma_kernel(const float* __restrict__ x,
                      const unsigned short* __restrict__ wp,
                      float* __restrict__ out) {
    __shared__ float red[8 * 1024];             // 32KB: 8 waves x (32 b0 x 32 col)

    const int b  = blockIdx.x;                  // 0..1567
    const int ct = (b & 7) * 196 + (b >> 3);    // XCD chunk swizzle (1568 = 8*196)

    const int t     = threadIdx.x;              // 0..511
    const int lane  = t & 63;
    const int wid   = t >> 6;                   // 0..7
    const int ccb   = wid;                      // K-slice = one 32-ch block
    const int col   = lane & 31;                // B-col / D-col
    const int khalf = lane >> 5;                // k-half 0..1
    const int s0    = ct * 32;                  // block's base column
    const int n     = s0 / HW2;                 // block-uniform (3136 = 98*32)
    const int s0img = s0 - n * HW2;
    const int sl    = s0img + col;              // lane's spatial idx in image
    const int h     = sl / HW;
    const int w     = sl - h * HW;
    const float* xn = x + (size_t)n * (C_IN * HW2);
    const short8* wpv = (const short8*)wp;

    f32x16 acc = {0.f,0.f,0.f,0.f, 0.f,0.f,0.f,0.f, 0.f,0.f,0.f,0.f, 0.f,0.f,0.f,0.f};

    const int cc = ccb * 32;
    #pragma unroll
    for (int dd = 0; dd < 3; ++dd) {            // di = dd-1
        const int di     = dd - 1;
        const int rowpos = sl + di * HW;        // pos at dj=0
        const int posm   = rowpos - 1;          // window base (dj=-1)
        const int pc     = posm < 0 ? 0 : (posm > HW2 - 4 ? HW2 - 4 : posm);
        const bool shifted = (pc != posm);      // edge lanes only
        const int ih = h + di;

        #pragma unroll
        for (int ch16 = 0; ch16 < 2; ++ch16) {
            f32x4 V[8];
            #pragma unroll
            for (int j = 0; j < 8; ++j) {
                const int ch = cc + ch16 * 16 + khalf * 8 + j;
                V[j] = *(const f32x4u*)(xn + (size_t)ch * HW2 + pc);
            }

            #pragma unroll
            for (int dd2 = 0; dd2 < 3; ++dd2) { // dj = dd2-1
                const int dj = dd2 - 1;
                const int iw = w + dj;
                const bool ok = ((unsigned)ih < (unsigned)HW) & ((unsigned)iw < (unsigned)HW);
                const int voff = rowpos + dj;

                short8 bf;
                #pragma unroll
                for (int j = 0; j < 8; ++j) {
                    float v = V[j][dd2];        // = x[ch][voff] when !shifted
                    if (shifted) {              // exec-masked scalar fallback
                        const int vc = voff < 0 ? 0 : (voff > HW2 - 1 ? HW2 - 1 : voff);
                        v = xn[(size_t)(cc + ch16 * 16 + khalf * 8 + j) * HW2 + vc];
                    }
                    v = ok ? v : 0.f;
                    const unsigned u = __builtin_bit_cast(unsigned, v);
                    bf[j] = (short)((u + 0x8000u) >> 16);   // fp32->bf16 round
                }

                const int Q = ccb * 18 + (dd * 3 + dd2) * 2 + ch16;
                const short8 a = wpv[Q * 64 + lane];
                acc = __builtin_amdgcn_mfma_f32_32x32x16_bf16(a, bf, acc, 0, 0, 0);
            }
        }
    }

    // ---- in-block K-reduce ----
    // C/D: col = lane&31, row b0 = (reg&3) + 8*(reg>>2) + 4*khalf (r12-proven)
    const int base = wid * 1024;
    #pragma unroll
    for (int i2 = 0; i2 < 16; ++i2) {
        const int b0 = (i2 & 3) + 8 * (i2 >> 2) + 4 * khalf;
        red[base + b0 * 32 + col] = acc[i2];
    }
    __syncthreads();

    float* on = out + (size_t)n * (BKT * HW2) + s0img;
    #pragma unroll
    for (int e = 0; e < 2; ++e) {
        const int elem = e * 512 + t;           // 0..1023 = b0*32 + c
        float s = red[elem];
        #pragma unroll
        for (int w2 = 1; w2 < 8; ++w2) s += red[w2 * 1024 + elem];
        const int b0 = elem >> 5;
        const int c  = elem & 31;
        on[(size_t)b0 * HW2 + c] = s;
    }
}

// ---------------------------------------------------------------------------
extern "C" void kernel_launch(void* const* d_in, const int* in_sizes, int n_in,
                              void* d_out, int out_size, void* d_ws, size_t ws_size,
                              hipStream_t stream) {
    const float* x       = (const float*)d_in[0];
    const float* kernels = (const float*)d_in[1];
    const float* a       = (const float*)d_in[2];
    const int*   table   = (const int*)d_in[3];
    float* out = (float*)d_out;
    int*   rows = (int*)d_ws;
    unsigned short* wpack = (unsigned short*)((char*)d_ws + 512);

    hipLaunchKernelGGL(hash_rows_kernel, dim3(1), dim3(256), 0, stream,
                       x, a, table, rows);
    hipLaunchKernelGGL(build_wpack_kernel, dim3(288), dim3(256), 0, stream,
                       kernels, rows, wpack);
    hipLaunchKernelGGL(alsh_mfma_kernel, dim3(1568), dim3(512), 0, stream,
                       x, wpack, out);
}